// Round 1
// baseline (210.030 us; speedup 1.0000x reference)
//
#include <hip/hip_runtime.h>
#include <hip/hip_bf16.h>

// u_dot_v edge scoring: out[e] = dot(x[src[e]], x[dst[e]]), D = 128 fp32.
// Layout: 32 lanes per edge; lane i loads float4 at row offset 4*i (16 B/lane,
// 512 B coalesced per row), fma-accumulates, then 5-step shfl_xor reduction
// within the 32-lane group (offsets 16..1 stay inside each wave64 half).
// 256-thread blocks -> 8 edges/block.

#define D_FEAT 128

__global__ __launch_bounds__(256)
void u_dot_v_kernel(const float* __restrict__ x,
                    const int* __restrict__ src,
                    const int* __restrict__ dst,
                    float* __restrict__ out,
                    int n_edges) {
    int gtid = blockIdx.x * blockDim.x + threadIdx.x;
    int edge = gtid >> 5;        // 32 lanes per edge
    int lane = gtid & 31;
    if (edge >= n_edges) return;

    int s = src[edge];
    int d = dst[edge];

    const float4* xs = reinterpret_cast<const float4*>(x + (size_t)s * D_FEAT);
    const float4* xd = reinterpret_cast<const float4*>(x + (size_t)d * D_FEAT);

    float4 a = xs[lane];
    float4 b = xd[lane];

    float sum = a.x * b.x + a.y * b.y + a.z * b.z + a.w * b.w;

    // Reduce across the 32-lane edge group. xor offsets <= 16 keep lanes
    // within their own half of the 64-lane wave, so the two edges sharing a
    // wave reduce independently.
    #pragma unroll
    for (int off = 16; off > 0; off >>= 1)
        sum += __shfl_xor(sum, off, 64);

    if (lane == 0) out[edge] = sum;
}

extern "C" void kernel_launch(void* const* d_in, const int* in_sizes, int n_in,
                              void* d_out, int out_size, void* d_ws, size_t ws_size,
                              hipStream_t stream) {
    const float* x   = (const float*)d_in[0];
    const int*   src = (const int*)d_in[1];
    const int*   dst = (const int*)d_in[2];
    float*       out = (float*)d_out;

    int n_edges = in_sizes[1];           // 1,000,000
    int threads = 256;                   // 8 edges per block
    long long total = (long long)n_edges * 32;
    int blocks = (int)((total + threads - 1) / threads);

    u_dot_v_kernel<<<blocks, threads, 0, stream>>>(x, src, dst, out, n_edges);
}

// Round 2
// 206.765 us; speedup vs baseline: 1.0158x; 1.0158x over previous
//
#include <hip/hip_runtime.h>
#include <hip/hip_bf16.h>

// u_dot_v edge scoring: out[e] = dot(x[src[e]], x[dst[e]]), D = 128 fp32.
//
// Round 2: ILP variant. 8 lanes per edge; lane i loads float4 at row offsets
// i, i+8, i+16, i+24 from BOTH rows -> 8 independent 16B loads per thread
// (128 B of gather in flight per thread, 4x round-1). The 8 lanes still cover
// each 512 B row contiguously (fully coalesced). 3-step shfl_xor reduction
// (offsets 4,2,1 stay inside the 8-lane group). 256-thread blocks -> 32
// edges/block, grid = 1M*8/256 = 31250 blocks.

#define D_FEAT 128

__global__ __launch_bounds__(256)
void u_dot_v_kernel(const float* __restrict__ x,
                    const int* __restrict__ src,
                    const int* __restrict__ dst,
                    float* __restrict__ out,
                    int n_edges) {
    int gtid = blockIdx.x * blockDim.x + threadIdx.x;
    int edge = gtid >> 3;        // 8 lanes per edge
    int lane = gtid & 7;
    if (edge >= n_edges) return;

    int s = src[edge];
    int d = dst[edge];

    const float4* xs = reinterpret_cast<const float4*>(x + (size_t)s * D_FEAT);
    const float4* xd = reinterpret_cast<const float4*>(x + (size_t)d * D_FEAT);

    // 8 independent loads — all issued before any use.
    float4 a0 = xs[lane];
    float4 a1 = xs[lane + 8];
    float4 a2 = xs[lane + 16];
    float4 a3 = xs[lane + 24];
    float4 b0 = xd[lane];
    float4 b1 = xd[lane + 8];
    float4 b2 = xd[lane + 16];
    float4 b3 = xd[lane + 24];

    float sum = a0.x * b0.x + a0.y * b0.y + a0.z * b0.z + a0.w * b0.w
              + a1.x * b1.x + a1.y * b1.y + a1.z * b1.z + a1.w * b1.w
              + a2.x * b2.x + a2.y * b2.y + a2.z * b2.z + a2.w * b2.w
              + a3.x * b3.x + a3.y * b3.y + a3.z * b3.z + a3.w * b3.w;

    // Reduce across the 8-lane edge group (xor offsets < 8 stay in-group).
    #pragma unroll
    for (int off = 4; off > 0; off >>= 1)
        sum += __shfl_xor(sum, off, 64);

    if (lane == 0) out[edge] = sum;
}

extern "C" void kernel_launch(void* const* d_in, const int* in_sizes, int n_in,
                              void* d_out, int out_size, void* d_ws, size_t ws_size,
                              hipStream_t stream) {
    const float* x   = (const float*)d_in[0];
    const int*   src = (const int*)d_in[1];
    const int*   dst = (const int*)d_in[2];
    float*       out = (float*)d_out;

    int n_edges = in_sizes[1];           // 1,000,000
    int threads = 256;                   // 32 edges per block
    long long total = (long long)n_edges * 8;
    int blocks = (int)((total + threads - 1) / threads);

    u_dot_v_kernel<<<blocks, threads, 0, stream>>>(x, src, dst, out, n_edges);
}

// Round 3
// 149.249 us; speedup vs baseline: 1.4072x; 1.3854x over previous
//
#include <hip/hip_runtime.h>
#include <hip/hip_bf16.h>
#include <hip/hip_fp16.h>

// u_dot_v edge scoring: out[e] = dot(x[src[e]], x[dst[e]]), D = 128 fp32.
//
// Round 3: the gather is L2-miss-bandwidth bound (two structurally different
// fp32 kernels both pinned at 3.6 TB/s FETCH BW; FETCH ~= 8 XCD x 51.2 MB =
// compulsory traffic for per-XCD L2s). So halve the bytes: convert x to fp16
// in a streaming pre-pass (51.2 -> 25.6 MB in d_ws), then gather 256 B rows.
// Accuracy: threshold is 3.26 (2% of max|score|); fp16 dot error ~0.02-0.3.

#define D_FEAT 128

typedef _Float16 half8 __attribute__((ext_vector_type(8)));   // 16 B

// ---- pre-pass: fp32 -> fp16, 8 floats per thread (2x float4 in, 16 B out)
__global__ __launch_bounds__(256)
void cvt_f32_to_f16(const float* __restrict__ x,
                    _Float16* __restrict__ xh,
                    int n) {                      // n = total floats
    int i = blockIdx.x * blockDim.x + threadIdx.x;   // handles floats [8i, 8i+8)
    int base = i * 8;
    if (base >= n) return;
    const float4* xv = reinterpret_cast<const float4*>(x);
    float4 v0 = xv[i * 2];
    float4 v1 = xv[i * 2 + 1];
    half8 h;
    h[0] = (_Float16)v0.x; h[1] = (_Float16)v0.y;
    h[2] = (_Float16)v0.z; h[3] = (_Float16)v0.w;
    h[4] = (_Float16)v1.x; h[5] = (_Float16)v1.y;
    h[6] = (_Float16)v1.z; h[7] = (_Float16)v1.w;
    reinterpret_cast<half8*>(xh)[i] = h;
}

// ---- gather-dot on fp16 rows (256 B). 8 lanes/edge; lane loads 16 B chunks
// at offsets {lane, lane+8} of 16 from both rows -> 4 x 16 B loads/thread,
// rows fully coalesced. 3-step shfl_xor reduction within the 8-lane group.
__global__ __launch_bounds__(256)
void u_dot_v_f16(const _Float16* __restrict__ xh,
                 const int* __restrict__ src,
                 const int* __restrict__ dst,
                 float* __restrict__ out,
                 int n_edges) {
    int gtid = blockIdx.x * blockDim.x + threadIdx.x;
    int edge = gtid >> 3;
    int lane = gtid & 7;
    if (edge >= n_edges) return;

    int s = src[edge];
    int d = dst[edge];

    const half8* xs = reinterpret_cast<const half8*>(xh + (size_t)s * D_FEAT);
    const half8* xd = reinterpret_cast<const half8*>(xh + (size_t)d * D_FEAT);

    half8 a0 = xs[lane];
    half8 a1 = xs[lane + 8];
    half8 b0 = xd[lane];
    half8 b1 = xd[lane + 8];

    float sum = 0.0f;
    #pragma unroll
    for (int k = 0; k < 8; ++k)
        sum += (float)a0[k] * (float)b0[k] + (float)a1[k] * (float)b1[k];

    #pragma unroll
    for (int off = 4; off > 0; off >>= 1)
        sum += __shfl_xor(sum, off, 64);

    if (lane == 0) out[edge] = sum;
}

// ---- fp32 fallback (round-2 kernel) if d_ws is too small for the fp16 table
__global__ __launch_bounds__(256)
void u_dot_v_f32(const float* __restrict__ x,
                 const int* __restrict__ src,
                 const int* __restrict__ dst,
                 float* __restrict__ out,
                 int n_edges) {
    int gtid = blockIdx.x * blockDim.x + threadIdx.x;
    int edge = gtid >> 3;
    int lane = gtid & 7;
    if (edge >= n_edges) return;

    int s = src[edge];
    int d = dst[edge];

    const float4* xs = reinterpret_cast<const float4*>(x + (size_t)s * D_FEAT);
    const float4* xd = reinterpret_cast<const float4*>(x + (size_t)d * D_FEAT);

    float4 a0 = xs[lane];
    float4 a1 = xs[lane + 8];
    float4 a2 = xs[lane + 16];
    float4 a3 = xs[lane + 24];
    float4 b0 = xd[lane];
    float4 b1 = xd[lane + 8];
    float4 b2 = xd[lane + 16];
    float4 b3 = xd[lane + 24];

    float sum = a0.x * b0.x + a0.y * b0.y + a0.z * b0.z + a0.w * b0.w
              + a1.x * b1.x + a1.y * b1.y + a1.z * b1.z + a1.w * b1.w
              + a2.x * b2.x + a2.y * b2.y + a2.z * b2.z + a2.w * b2.w
              + a3.x * b3.x + a3.y * b3.y + a3.z * b3.z + a3.w * b3.w;

    #pragma unroll
    for (int off = 4; off > 0; off >>= 1)
        sum += __shfl_xor(sum, off, 64);

    if (lane == 0) out[edge] = sum;
}

extern "C" void kernel_launch(void* const* d_in, const int* in_sizes, int n_in,
                              void* d_out, int out_size, void* d_ws, size_t ws_size,
                              hipStream_t stream) {
    const float* x   = (const float*)d_in[0];
    const int*   src = (const int*)d_in[1];
    const int*   dst = (const int*)d_in[2];
    float*       out = (float*)d_out;

    int n_x     = in_sizes[0];           // 100000 * 128 = 12,800,000 floats
    int n_edges = in_sizes[1];           // 1,000,000

    size_t need = (size_t)n_x * sizeof(_Float16);   // 25.6 MB

    if (ws_size >= need && (n_x % 8) == 0) {
        _Float16* xh = (_Float16*)d_ws;

        int cvt_threads = 256;
        int cvt_items   = n_x / 8;                       // 1.6M threads
        int cvt_blocks  = (cvt_items + cvt_threads - 1) / cvt_threads;
        cvt_f32_to_f16<<<cvt_blocks, cvt_threads, 0, stream>>>(x, xh, n_x);

        int threads = 256;
        long long total = (long long)n_edges * 8;
        int blocks = (int)((total + threads - 1) / threads);
        u_dot_v_f16<<<blocks, threads, 0, stream>>>(xh, src, dst, out, n_edges);
    } else {
        int threads = 256;
        long long total = (long long)n_edges * 8;
        int blocks = (int)((total + threads - 1) / threads);
        u_dot_v_f32<<<blocks, threads, 0, stream>>>(x, src, dst, out, n_edges);
    }
}